// Round 4
// baseline (266.430 us; speedup 1.0000x reference)
//
#include <hip/hip_runtime.h>

#define BB 4
#define LL 2048
#define DD 1024
#define HH 16
#define HD 64

typedef __attribute__((ext_vector_type(8))) short s16x8;
typedef __attribute__((ext_vector_type(4))) short s16x4;
typedef __attribute__((ext_vector_type(4))) float f32x4;

#define SCALE_LOG2E 0.18033688011112042f  // 0.125 * log2(e), folded into Q

__device__ __forceinline__ short f2bf(float f) {
  union { float f; unsigned u; } c;
  c.f = f;
  return (short)((c.u + 0x7fffu + ((c.u >> 16) & 1u)) >> 16);  // RNE
}

// async global -> LDS, 16B per lane. LDS dest = wave-uniform base + lane*16.
__device__ __forceinline__ void cp16(const void* g, void* l) {
  __builtin_amdgcn_global_load_lds(
      (const __attribute__((address_space(1))) void*)g,
      (__attribute__((address_space(3))) void*)l, 16, 0, 0);
}

template <int N>
__device__ __forceinline__ void waitvm() {
  static_assert(N == 0 || N == 3 || N == 4, "vmcnt imm");
  if constexpr (N == 0) asm volatile("s_waitcnt vmcnt(0)" ::: "memory");
  else if constexpr (N == 3) asm volatile("s_waitcnt vmcnt(3)" ::: "memory");
  else if constexpr (N == 4) asm volatile("s_waitcnt vmcnt(4)" ::: "memory");
}

#define BAR()                                  \
  do {                                         \
    asm volatile("" ::: "memory");             \
    __builtin_amdgcn_s_barrier();              \
    asm volatile("" ::: "memory");             \
  } while (0)

// ---------------- fp32 -> bf16 convert ----------------
__global__ __launch_bounds__(256) void f2b_kernel(const float* __restrict__ in,
                                                  short* __restrict__ out, int n4) {
  int i = blockIdx.x * blockDim.x + threadIdx.x;
  if (i >= n4) return;
  float4 v = ((const float4*)in)[i];
  s16x4 o;
  o[0] = f2bf(v.x);
  o[1] = f2bf(v.y);
  o[2] = f2bf(v.z);
  o[3] = f2bf(v.w);
  ((s16x4*)out)[i] = o;
}

// ---------------- GEMM, 8-phase schedule (m201 port) ------------------------
// C[M,N] = A[M,K] * B[N,K]^T, bf16 in. BN=256 fixed, BM in {256,128}.
// 512 threads = 8 waves (2M x 4N), wave-tile (BM/2) x 64. BK=64 K-tiles,
// LDS [2 buf][2 ksub][rows*32] (A: BM rows, B: 256 rows). Iteration = 2
// K-tiles (even->buf0, odd->buf1) in 8 phases; each phase: {ds_read one
// frag set | stage one half-tile} -> barrier -> setprio+16..32 MFMA (one
// acc col-pair; consecutive phases hit disjoint acc regs) -> barrier.
// Stage order per tile: A.k0, B.k0, A.k1, B.k1 at consecutive phases;
// vmcnt(LA+LB) at end of every odd phase retires exactly the half-tiles
// the next two phases read (LA+LB loads stay in flight; never drained
// except last-iter phi5 -> vmcnt(0)). Overwrite safety: every half-tile
// has >=2 barriers between last read and rewrite (ledger in session notes).
// SWIZZLE (proven 0-conflict in r2/r3): granule ^= (row>>1)&3 on staged
// source and LDS read.
// MODE 0: scatter bf16 into Q (pre-scaled) / K [B,H,L,HD], V^T [B,H,HD,L].
// MODE 1: fp32 row-major out.
template <int BM, int MODE>
__global__ __launch_bounds__(512, 2) void gemm8(const short* __restrict__ A,
                                                const short* __restrict__ Bm,
                                                int K, int N,
                                                short* __restrict__ qo,
                                                short* __restrict__ ko,
                                                short* __restrict__ vo,
                                                float* __restrict__ fo) {
  constexpr int MR = BM / 32;   // A frags per wave (rows/16 of wave-tile)
  constexpr int LA = BM / 128;  // cp16 per thread per A half-stage
  constexpr int VM = LA + 2;    // steady vmcnt level

  __shared__ __align__(16) short As[2][2][BM * 32];
  __shared__ __align__(16) short Bs[2][2][256 * 32];
  const int tid = threadIdx.x;
  const int m0 = blockIdx.y * BM, n0 = blockIdx.x * 256;
  const int wave = tid >> 6, lane = tid & 63;
  const int quad = lane >> 4, c16 = lane & 15;
  const int wr = (wave >> 2) * (BM / 2), wc = (wave & 3) * 64;

  f32x4 zero = {0.f, 0.f, 0.f, 0.f};
  f32x4 acc[MR][4];
#pragma unroll
  for (int i = 0; i < MR; i++)
#pragma unroll
    for (int j = 0; j < 4; j++) acc[i][j] = zero;

  // staging: per cp16 a wave covers 16 rows x 4 granules (lane l: row l>>2,
  // granule l&3), source granule pre-swizzled by (row>>1)&3.
  const int srow = wave * 16 + (lane >> 2);
  const int gsw = ((lane & 3) ^ ((lane >> 3) & 3)) * 8;
  const short* Ag = A + (size_t)(m0 + srow) * K + gsw;
  const short* Bg = Bm + (size_t)(n0 + srow) * K + gsw;
  const int rsw = (quad ^ ((c16 >> 1) & 3)) * 8;  // read-side swizzle

  auto stageA = [&](int t, int s) {
    const int bi = t & 1, k0 = t * 64 + s * 32;
#pragma unroll
    for (int i = 0; i < LA; i++)
      cp16(Ag + (size_t)(i * 128) * K + k0, &As[bi][s][(i * 128 + wave * 16) * 32]);
  };
  auto stageB = [&](int t, int s) {
    const int bi = t & 1, k0 = t * 64 + s * 32;
#pragma unroll
    for (int i = 0; i < 2; i++)
      cp16(Bg + (size_t)(i * 128) * K + k0, &Bs[bi][s][(i * 128 + wave * 16) * 32]);
  };

  s16x8 af[MR];
  auto rdA = [&](int bi, int s) {
#pragma unroll
    for (int i = 0; i < MR; i++)
      af[i] = *(const s16x8*)&As[bi][s][(wr + i * 16 + c16) * 32 + rsw];
  };
  auto rdB = [&](int bi, int s, int j) {
    return *(const s16x8*)&Bs[bi][s][(wc + j * 16 + c16) * 32 + rsw];
  };
  auto mm2 = [&](s16x8 b0, s16x8 b1, int c) {
    __builtin_amdgcn_s_setprio(1);
#pragma unroll
    for (int i = 0; i < MR; i++) {
      acc[i][2 * c] = __builtin_amdgcn_mfma_f32_16x16x32_bf16(af[i], b0, acc[i][2 * c], 0, 0, 0);
      acc[i][2 * c + 1] =
          __builtin_amdgcn_mfma_f32_16x16x32_bf16(af[i], b1, acc[i][2 * c + 1], 0, 0, 0);
    }
    __builtin_amdgcn_s_setprio(0);
  };

  // prologue: tile 0's 4 half-tiles in steady-state order
  stageA(0, 0);
  stageB(0, 0);
  stageA(0, 1);
  stageB(0, 1);
  waitvm<VM>();
  BAR();

  const int J = K >> 7;  // iterations of 2 K-tiles
  for (int j = 0; j < J; j++) {
    const bool last = (j == J - 1);
    const int to = 2 * j + 1, te = 2 * j + 2;
    s16x8 b0, b1;
    // phi0: even tile, ksub0, cols 0-1
    rdA(0, 0);
    b0 = rdB(0, 0, 0);
    b1 = rdB(0, 0, 1);
    stageA(to, 0);
    BAR();
    mm2(b0, b1, 0);
    BAR();
    // phi1: even, ksub0, cols 2-3
    b0 = rdB(0, 0, 2);
    b1 = rdB(0, 0, 3);
    stageB(to, 0);
    BAR();
    mm2(b0, b1, 1);
    waitvm<VM>();
    BAR();
    // phi2: even, ksub1, cols 0-1
    rdA(0, 1);
    b0 = rdB(0, 1, 0);
    b1 = rdB(0, 1, 1);
    stageA(to, 1);
    BAR();
    mm2(b0, b1, 0);
    BAR();
    // phi3: even, ksub1, cols 2-3
    b0 = rdB(0, 1, 2);
    b1 = rdB(0, 1, 3);
    stageB(to, 1);
    BAR();
    mm2(b0, b1, 1);
    waitvm<VM>();
    BAR();
    // phi4: odd tile, ksub0, cols 0-1
    rdA(1, 0);
    b0 = rdB(1, 0, 0);
    b1 = rdB(1, 0, 1);
    if (!last) stageA(te, 0);
    BAR();
    mm2(b0, b1, 0);
    BAR();
    // phi5: odd, ksub0, cols 2-3
    b0 = rdB(1, 0, 2);
    b1 = rdB(1, 0, 3);
    if (!last) stageB(te, 0);
    BAR();
    mm2(b0, b1, 1);
    if (last) waitvm<0>();
    else waitvm<VM>();
    BAR();
    // phi6: odd, ksub1, cols 0-1
    rdA(1, 1);
    b0 = rdB(1, 1, 0);
    b1 = rdB(1, 1, 1);
    if (!last) stageA(te, 1);
    BAR();
    mm2(b0, b1, 0);
    BAR();
    // phi7: odd, ksub1, cols 2-3
    b0 = rdB(1, 1, 2);
    b1 = rdB(1, 1, 3);
    if (!last) stageB(te, 1);
    BAR();
    mm2(b0, b1, 1);
    if (!last) waitvm<VM>();
    BAR();
  }

  if (MODE == 0) {
#pragma unroll
    for (int j = 0; j < 4; j++) {
      const int gn = n0 + wc + j * 16 + c16;  // 0..3071
      const int which = gn >> 10;
      const int h = (gn >> 6) & 15;
      const int hd = gn & 63;
      if (which == 2) {
#pragma unroll
        for (int i = 0; i < MR; i++) {
          const int gm = m0 + wr + i * 16 + quad * 4;  // 4 consecutive rows
          const int b = gm >> 11, l = gm & 2047;       // l..l+3 contiguous, 8B-aligned
          s16x4 vv;
#pragma unroll
          for (int r = 0; r < 4; r++) vv[r] = f2bf(acc[i][j][r]);
          *(s16x4*)&vo[((size_t)((b << 4) + h) * HD + hd) * LL + l] = vv;
        }
      } else {
        short* dst = which == 0 ? qo : ko;
        const float sc = which == 0 ? SCALE_LOG2E : 1.0f;  // fold softmax scale into Q
#pragma unroll
        for (int i = 0; i < MR; i++)
#pragma unroll
          for (int r = 0; r < 4; r++) {
            const int gm = m0 + wr + i * 16 + quad * 4 + r;
            const int b = gm >> 11, l = gm & 2047;
            dst[((size_t)((b << 4) + h) * LL + l) * HD + hd] = f2bf(acc[i][j][r] * sc);
          }
      }
    }
  } else {
#pragma unroll
    for (int i = 0; i < MR; i++)
#pragma unroll
      for (int r = 0; r < 4; r++) {
        const int gm = m0 + wr + i * 16 + quad * 4 + r;
#pragma unroll
        for (int j = 0; j < 4; j++) {
          const int gn = n0 + wc + j * 16 + c16;
          fo[(size_t)gm * N + gn] = acc[i][j][r];
        }
      }
  }
}

// ---------------- flash attention: paired q-blocks, 128-key tiles ----------
// Causal load balance: block pi processes q-block (15-pi) then q-block pi —
// exactly 17 tile-rounds per block, grid 8x64 = 512 blocks = 2/CU.
// 8 waves x 16 queries each -> 16 waves/CU = 4/SIMD for latency hiding.
// S^T = K*Q^T per 16-key block; P in registers; Q pre-scaled; p = 2^s
// (exact after p/l norm); denom via ones-A MFMA on the matrix pipe.
__global__ __launch_bounds__(512, 4) void attn_kernel(const short* __restrict__ Qb,
                                                      const short* __restrict__ Kb,
                                                      const short* __restrict__ Vtb,
                                                      short* __restrict__ Cb) {
  const int pi = blockIdx.x;  // 0..7
  const int bh = blockIdx.y;  // 0..63
  const int tid = threadIdx.x;
  const int wave = tid >> 6, lane = tid & 63;  // wave 0..7
  const int quad = lane >> 4, c16 = lane & 15;
  const int sw = c16 & 7;  // K-read swizzle term
  const size_t base = (size_t)bh * LL * HD;
  const short* Q = Qb + base;
  const short* K = Kb + base;
  const short* Vt = Vtb + base;  // [HD][LL]

  __shared__ __align__(16) short Ks[2][128 * 64];  // [key][hd], 3-bit swizzle
  __shared__ __align__(16) short Vs[2][64 * 128];  // [hd][key], 4-bit swizzle

  const f32x4 zero = {0.f, 0.f, 0.f, 0.f};
  const s16x4 ones = {(short)0x3F80, (short)0x3F80, (short)0x3F80, (short)0x3F80};

  // staging (512 threads): K 2 issues (64 rows x 128B each), V 2 issues
  // (32 rows x 256B each); swizzle terms hoisted (gk&7==k_r, gv&15 const/i).
  const int k_r = lane >> 3, k_c = lane & 7;    // K: 8-row slab, 8 16B granules
  const int v_r = lane >> 4, v_c = lane & 15;   // V: 4-row slab, 16 16B granules
  const int ksw = (k_c ^ k_r) * 8;
  const int vsw = (v_c ^ ((wave * 4 + v_r) & 15)) * 8;
  auto stage = [&](int kb, int bi) {
#pragma unroll
    for (int i = 0; i < 2; i++) {
      const int gk = i * 64 + wave * 8 + k_r;
      cp16(K + (size_t)(kb + gk) * HD + ksw, &Ks[bi][(i * 64 + wave * 8) * 64]);
      const int gv = i * 32 + wave * 4 + v_r;
      cp16(Vt + (size_t)gv * LL + kb + vsw, &Vs[bi][(i * 32 + wave * 4) * 128]);
    }
  };

  // pack 4 f32 -> 4 truncated bf16 via 2 x v_perm_b32
  auto pack4 = [&](const float* p) {
    union { float f; unsigned u; } a0, a1, a2, a3;
    a0.f = p[0]; a1.f = p[1]; a2.f = p[2]; a3.f = p[3];
    union { s16x4 v; unsigned u[2]; } r;
    r.u[0] = __builtin_amdgcn_perm(a1.u, a0.u, 0x07060302u);
    r.u[1] = __builtin_amdgcn_perm(a3.u, a2.u, 0x07060302u);
    return r.v;
  };

  for (int phase = 0; phase < 2; phase++) {
    const int qg = phase == 0 ? (15 - pi) : pi;  // heavy first
    const int qw = qg * 128 + wave * 16;         // this wave's 16 queries
    const int tiles = qg + 1;                    // 128-key tiles

    s16x8 qf[2];
#pragma unroll
    for (int s = 0; s < 2; s++)
      qf[s] = *(const s16x8*)(Q + (size_t)(qw + c16) * HD + s * 32 + quad * 8);

    f32x4 o[4];
#pragma unroll
    for (int j4 = 0; j4 < 4; j4++) o[j4] = zero;
    f32x4 ol = zero;

    stage(0, 0);
    __syncthreads();  // drain tile 0 (also isolates phase 0's last readers)

    for (int t = 0; t < tiles; t++) {
      const int kb = t * 128;
      if (t + 1 < tiles) stage(kb + 128, (t + 1) & 1);
      const short* Kt = &Ks[t & 1][0];
      const short* Vv = &Vs[t & 1][0];

      // causal bounds (wave-uniform): this wave covers queries qw..qw+15
      const int D = qw - kb;                       // >= 0 within tiles range
      const int jm = min((D >> 4) + 1, 8);
      const int jb = D >> 4;

#pragma unroll
      for (int j = 0; j < 8; j++) {
        if (j >= jm) continue;  // wave-uniform skip
        s16x8 kf0 = *(const s16x8*)&Kt[(j * 16 + c16) * 64 + ((quad ^ sw) * 8)];
        s16x8 kf1 = *(const s16x8*)&Kt[(j * 16 + c16) * 64 + (((4 + quad) ^ sw) * 8)];
        s16x4 va[4];
#pragma unroll
        for (int j4 = 0; j4 < 4; j4++)
          va[j4] = *(const s16x4*)&Vv[(j4 * 16 + c16) * 128 +
                                      (((2 * j + (quad >> 1)) ^ c16) * 8) + (quad & 1) * 4];
        f32x4 s = __builtin_amdgcn_mfma_f32_16x16x32_bf16(kf0, qf[0], zero, 0, 0, 0);
        s = __builtin_amdgcn_mfma_f32_16x16x32_bf16(kf1, qf[1], s, 0, 0, 0);
        float p[4];
#pragma unroll
        for (int r = 0; r < 4; r++) p[r] = __builtin_amdgcn_exp2f(s[r]);
        if (j == jb) {
          const int thr = c16 + D - j * 16 - quad * 4;
#pragma unroll
          for (int r = 0; r < 4; r++)
            if (r > thr) p[r] = 0.f;
        }
        s16x4 pb = pack4(p);
        ol = __builtin_amdgcn_mfma_f32_16x16x16bf16_1k(ones, pb, ol, 0, 0, 0);
#pragma unroll
        for (int j4 = 0; j4 < 4; j4++)
          o[j4] = __builtin_amdgcn_mfma_f32_16x16x16bf16_1k(va[j4], pb, o[j4], 0, 0, 0);
      }

      __syncthreads();  // readers done with buf t; drains t+1 staging
    }

    const int b = bh >> 4, h2 = bh & 15;
    const float inv = 1.0f / ol[0];
    const int q = qw + c16;
#pragma unroll
    for (int j4 = 0; j4 < 4; j4++) {
      s16x4 ov;
#pragma unroll
      for (int r = 0; r < 4; r++) ov[r] = f2bf(o[j4][r] * inv);
      *(s16x4*)&Cb[(size_t)(b * LL + q) * DD + h2 * HD + j4 * 16 + quad * 4] = ov;
    }
  }
}

// ---------------- launch ----------------
extern "C" void kernel_launch(void* const* d_in, const int* in_sizes, int n_in,
                              void* d_out, int out_size, void* d_ws, size_t ws_size,
                              hipStream_t stream) {
  const float* x = (const float*)d_in[0];
  const float* wqkv = (const float*)d_in[1];
  const float* wout = (const float*)d_in[2];
  float* out = (float*)d_out;

  const size_t NX = (size_t)BB * LL * DD;  // 8388608
  short* xb = (short*)d_ws;
  short* wqkvb = xb + NX;
  short* woutb = wqkvb + (size_t)3 * DD * DD;
  short* qb = woutb + (size_t)DD * DD;
  short* kb = qb + NX;
  short* vb = kb + NX;   // V transposed: [B,H,HD,L]
  short* cb = vb + NX;
  // total: 92,274,688 bytes of d_ws

  f2b_kernel<<<dim3((unsigned)(NX / 4 / 256)), 256, 0, stream>>>(x, xb, (int)(NX / 4));
  f2b_kernel<<<dim3(3 * DD * DD / 4 / 256), 256, 0, stream>>>(wqkv, wqkvb, 3 * DD * DD / 4);
  f2b_kernel<<<dim3(DD * DD / 4 / 256), 256, 0, stream>>>(wout, woutb, DD * DD / 4);

  // gemm0: 256x256 tiles, 8-phase -> 12 x 32 = 384 blocks (128 KB LDS)
  gemm8<256, 0><<<dim3(3 * DD / 256, BB * LL / 256), 512, 0, stream>>>(
      xb, wqkvb, DD, 3 * DD, qb, kb, vb, nullptr);
  attn_kernel<<<dim3(8, BB * HH), 512, 0, stream>>>(qb, kb, vb, cb);
  // gemm1: 128x256 tiles, 8-phase -> 4 x 64 = 256 blocks = one exact round
  gemm8<128, 1><<<dim3(DD / 256, BB * LL / 128), 512, 0, stream>>>(
      cb, woutb, DD, DD, nullptr, nullptr, nullptr, out);
}

// Round 5
// 260.294 us; speedup vs baseline: 1.0236x; 1.0236x over previous
//
#include <hip/hip_runtime.h>

#define BB 4
#define LL 2048
#define DD 1024
#define HH 16
#define HD 64

typedef __attribute__((ext_vector_type(8))) short s16x8;
typedef __attribute__((ext_vector_type(4))) short s16x4;
typedef __attribute__((ext_vector_type(4))) float f32x4;

#define SCALE_LOG2E 0.18033688011112042f  // 0.125 * log2(e), folded into Q

__device__ __forceinline__ short f2bf(float f) {
  union { float f; unsigned u; } c;
  c.f = f;
  return (short)((c.u + 0x7fffu + ((c.u >> 16) & 1u)) >> 16);  // RNE
}

// async global -> LDS, 16B per lane. LDS dest = wave-uniform base + lane*16.
__device__ __forceinline__ void cp16(const void* g, void* l) {
  __builtin_amdgcn_global_load_lds(
      (const __attribute__((address_space(1))) void*)g,
      (__attribute__((address_space(3))) void*)l, 16, 0, 0);
}

template <int N>
__device__ __forceinline__ void waitvm() {
  static_assert(N == 0 || N == 3 || N == 4, "vmcnt imm");
  if constexpr (N == 0) asm volatile("s_waitcnt vmcnt(0)" ::: "memory");
  else if constexpr (N == 3) asm volatile("s_waitcnt vmcnt(3)" ::: "memory");
  else if constexpr (N == 4) asm volatile("s_waitcnt vmcnt(4)" ::: "memory");
}

#define BAR()                                  \
  do {                                         \
    asm volatile("" ::: "memory");             \
    __builtin_amdgcn_s_barrier();              \
    asm volatile("" ::: "memory");             \
  } while (0)

// ---------------- fp32 -> bf16 convert ----------------
__global__ __launch_bounds__(256) void f2b_kernel(const float* __restrict__ in,
                                                  short* __restrict__ out, int n4) {
  int i = blockIdx.x * blockDim.x + threadIdx.x;
  if (i >= n4) return;
  float4 v = ((const float4*)in)[i];
  s16x4 o;
  o[0] = f2bf(v.x);
  o[1] = f2bf(v.y);
  o[2] = f2bf(v.z);
  o[3] = f2bf(v.w);
  ((s16x4*)out)[i] = o;
}

// ---------------- GEMM, 8-phase schedule, DEEP pipeline ---------------------
// C[M,N] = A[M,K] * B[N,K]^T, bf16 in. BN=256 fixed, BM in {256,128}.
// 512 threads = 8 waves (2M x 4N), wave-tile (BM/2) x 64. BK=64 K-tiles,
// LDS [2 buf][2 ksub]. Iteration = 2 K-tiles (E=2j -> buf0, O=2j+1 -> buf1),
// 8 phases; phase: {ds_read frag set | stage ONE half-stage} -> barrier ->
// setprio + MFMA col-pair -> barrier.
// DEEP LEDGER (the r4 defect was retire-distance 2-3 phases): staging runs
// 1.5-2 tiles ahead: phases 0..7 stage A(O,1) B(O,1) A(E+2,0) B(E+2,0)
// A(E+2,1) B(E+2,1) A(O+2,0) B(O+2,0). Waits ONLY at phi3/phi7, vmcnt(LA+2)
// = leave newest 2 issues in flight; each wait retires loads issued >=5
// phases (~1400cy) earlier. Residency verified: phi4 reads A/B(O,0) staged
// phi6/7(j-1) retired at phi3; phi6 reads A/B(O,1) staged phi0/1 retired at
// phi3; next-iter phi0/phi2 read (E+2) halves retired at phi7. Every slot
// rewrite is >=4 barriers after its last read. Last iter: only phi0/1 stage;
// phi3 drains vmcnt(0).
// Prologue: stage tile0 (4 halves) + tile1 ksub0 (2 halves), wait(LA+2).
// SWIZZLE (measured 0-conflict r2-r4): granule ^= (row>>1)&3 both sides.
// MODE 0: scatter bf16 into Q (pre-scaled) / K [B,H,L,HD], V^T [B,H,HD,L].
// MODE 1: fp32 row-major out.
template <int BM, int MODE>
__global__ __launch_bounds__(512, 2) void gemm8(const short* __restrict__ A,
                                                const short* __restrict__ Bm,
                                                int K, int N,
                                                short* __restrict__ qo,
                                                short* __restrict__ ko,
                                                short* __restrict__ vo,
                                                float* __restrict__ fo) {
  constexpr int MR = BM / 32;   // A frags per wave (rows/16 of wave-tile)
  constexpr int LA = BM / 128;  // cp16 per thread per A half-stage
  constexpr int VM = LA + 2;    // leave newest 2 issues (A+B) in flight

  __shared__ __align__(16) short As[2][2][BM * 32];
  __shared__ __align__(16) short Bs[2][2][256 * 32];
  const int tid = threadIdx.x;
  const int m0 = blockIdx.y * BM, n0 = blockIdx.x * 256;
  const int wave = tid >> 6, lane = tid & 63;
  const int quad = lane >> 4, c16 = lane & 15;
  const int wr = (wave >> 2) * (BM / 2), wc = (wave & 3) * 64;

  f32x4 zero = {0.f, 0.f, 0.f, 0.f};
  f32x4 acc[MR][4];
#pragma unroll
  for (int i = 0; i < MR; i++)
#pragma unroll
    for (int j = 0; j < 4; j++) acc[i][j] = zero;

  // staging: per cp16 a wave covers 16 rows x 4 granules (lane l: row l>>2,
  // granule l&3), source granule pre-swizzled by (row>>1)&3.
  const int srow = wave * 16 + (lane >> 2);
  const int gsw = ((lane & 3) ^ ((lane >> 3) & 3)) * 8;
  const short* Ag = A + (size_t)(m0 + srow) * K + gsw;
  const short* Bg = Bm + (size_t)(n0 + srow) * K + gsw;
  const int rsw = (quad ^ ((c16 >> 1) & 3)) * 8;  // read-side swizzle

  auto stageA = [&](int t, int s) {
    const int bi = t & 1, k0 = t * 64 + s * 32;
#pragma unroll
    for (int i = 0; i < LA; i++)
      cp16(Ag + (size_t)(i * 128) * K + k0, &As[bi][s][(i * 128 + wave * 16) * 32]);
  };
  auto stageB = [&](int t, int s) {
    const int bi = t & 1, k0 = t * 64 + s * 32;
#pragma unroll
    for (int i = 0; i < 2; i++)
      cp16(Bg + (size_t)(i * 128) * K + k0, &Bs[bi][s][(i * 128 + wave * 16) * 32]);
  };

  s16x8 af[MR];
  auto rdA = [&](int bi, int s) {
#pragma unroll
    for (int i = 0; i < MR; i++)
      af[i] = *(const s16x8*)&As[bi][s][(wr + i * 16 + c16) * 32 + rsw];
  };
  auto rdB = [&](int bi, int s, int j) {
    return *(const s16x8*)&Bs[bi][s][(wc + j * 16 + c16) * 32 + rsw];
  };
  auto mm2 = [&](s16x8 b0, s16x8 b1, int c) {
    __builtin_amdgcn_s_setprio(1);
#pragma unroll
    for (int i = 0; i < MR; i++) {
      acc[i][2 * c] = __builtin_amdgcn_mfma_f32_16x16x32_bf16(af[i], b0, acc[i][2 * c], 0, 0, 0);
      acc[i][2 * c + 1] =
          __builtin_amdgcn_mfma_f32_16x16x32_bf16(af[i], b1, acc[i][2 * c + 1], 0, 0, 0);
    }
    __builtin_amdgcn_s_setprio(0);
  };

  // prologue: tile 0 complete + tile 1 ksub0; retire tile 0, keep 2 in flight
  stageA(0, 0);
  stageB(0, 0);
  stageA(0, 1);
  stageB(0, 1);
  stageA(1, 0);
  stageB(1, 0);
  waitvm<VM>();
  BAR();

  const int J = K >> 7;  // iterations of 2 K-tiles (J >= 2)
  for (int j = 0; j < J; j++) {
    const bool last = (j == J - 1);
    const int to = 2 * j + 1, te = 2 * j + 2;
    s16x8 b0, b1;
    // phi0: E ksub0 cols01 | stage A(O,1)
    rdA(0, 0);
    b0 = rdB(0, 0, 0);
    b1 = rdB(0, 0, 1);
    stageA(to, 1);
    BAR();
    mm2(b0, b1, 0);
    BAR();
    // phi1: E ksub0 cols23 | stage B(O,1)
    b0 = rdB(0, 0, 2);
    b1 = rdB(0, 0, 3);
    stageB(to, 1);
    BAR();
    mm2(b0, b1, 1);
    BAR();
    // phi2: E ksub1 cols01 | stage A(E+2,0)
    rdA(0, 1);
    b0 = rdB(0, 1, 0);
    b1 = rdB(0, 1, 1);
    if (!last) stageA(te, 0);
    BAR();
    mm2(b0, b1, 0);
    BAR();
    // phi3: E ksub1 cols23 | stage B(E+2,0) | WAIT
    b0 = rdB(0, 1, 2);
    b1 = rdB(0, 1, 3);
    if (!last) stageB(te, 0);
    BAR();
    mm2(b0, b1, 1);
    if (last) waitvm<0>();
    else waitvm<VM>();
    BAR();
    // phi4: O ksub0 cols01 | stage A(E+2,1)
    rdA(1, 0);
    b0 = rdB(1, 0, 0);
    b1 = rdB(1, 0, 1);
    if (!last) stageA(te, 1);
    BAR();
    mm2(b0, b1, 0);
    BAR();
    // phi5: O ksub0 cols23 | stage B(E+2,1)
    b0 = rdB(1, 0, 2);
    b1 = rdB(1, 0, 3);
    if (!last) stageB(te, 1);
    BAR();
    mm2(b0, b1, 1);
    BAR();
    // phi6: O ksub1 cols01 | stage A(O+2,0)
    rdA(1, 1);
    b0 = rdB(1, 1, 0);
    b1 = rdB(1, 1, 1);
    if (!last) stageA(te + 1, 0);
    BAR();
    mm2(b0, b1, 0);
    BAR();
    // phi7: O ksub1 cols23 | stage B(O+2,0) | WAIT
    b0 = rdB(1, 1, 2);
    b1 = rdB(1, 1, 3);
    if (!last) stageB(te + 1, 0);
    BAR();
    mm2(b0, b1, 1);
    if (!last) waitvm<VM>();
    BAR();
  }

  if (MODE == 0) {
#pragma unroll
    for (int j = 0; j < 4; j++) {
      const int gn = n0 + wc + j * 16 + c16;  // 0..3071
      const int which = gn >> 10;
      const int h = (gn >> 6) & 15;
      const int hd = gn & 63;
      if (which == 2) {
#pragma unroll
        for (int i = 0; i < MR; i++) {
          const int gm = m0 + wr + i * 16 + quad * 4;  // 4 consecutive rows
          const int b = gm >> 11, l = gm & 2047;       // l..l+3 contiguous, 8B-aligned
          s16x4 vv;
#pragma unroll
          for (int r = 0; r < 4; r++) vv[r] = f2bf(acc[i][j][r]);
          *(s16x4*)&vo[((size_t)((b << 4) + h) * HD + hd) * LL + l] = vv;
        }
      } else {
        short* dst = which == 0 ? qo : ko;
        const float sc = which == 0 ? SCALE_LOG2E : 1.0f;  // fold softmax scale into Q
#pragma unroll
        for (int i = 0; i < MR; i++)
#pragma unroll
          for (int r = 0; r < 4; r++) {
            const int gm = m0 + wr + i * 16 + quad * 4 + r;
            const int b = gm >> 11, l = gm & 2047;
            dst[((size_t)((b << 4) + h) * LL + l) * HD + hd] = f2bf(acc[i][j][r] * sc);
          }
      }
    }
  } else {
#pragma unroll
    for (int i = 0; i < MR; i++)
#pragma unroll
      for (int r = 0; r < 4; r++) {
        const int gm = m0 + wr + i * 16 + quad * 4 + r;
#pragma unroll
        for (int j = 0; j < 4; j++) {
          const int gn = n0 + wc + j * 16 + c16;
          fo[(size_t)gm * N + gn] = acc[i][j][r];
        }
      }
  }
}

// ---------------- flash attention: paired q-blocks, 128-key tiles ----------
// Causal load balance: block pi processes q-block (15-pi) then q-block pi —
// exactly 17 tile-rounds per block, grid 8x64 = 512 blocks = 2/CU.
// 8 waves x 16 queries each -> 16 waves/CU = 4/SIMD for latency hiding.
// S^T = K*Q^T per 16-key block; P in registers; Q pre-scaled; p = 2^s
// (exact after p/l norm); denom via ones-A MFMA on the matrix pipe.
__global__ __launch_bounds__(512, 4) void attn_kernel(const short* __restrict__ Qb,
                                                      const short* __restrict__ Kb,
                                                      const short* __restrict__ Vtb,
                                                      short* __restrict__ Cb) {
  const int pi = blockIdx.x;  // 0..7
  const int bh = blockIdx.y;  // 0..63
  const int tid = threadIdx.x;
  const int wave = tid >> 6, lane = tid & 63;  // wave 0..7
  const int quad = lane >> 4, c16 = lane & 15;
  const int sw = c16 & 7;  // K-read swizzle term
  const size_t base = (size_t)bh * LL * HD;
  const short* Q = Qb + base;
  const short* K = Kb + base;
  const short* Vt = Vtb + base;  // [HD][LL]

  __shared__ __align__(16) short Ks[2][128 * 64];  // [key][hd], 3-bit swizzle
  __shared__ __align__(16) short Vs[2][64 * 128];  // [hd][key], 4-bit swizzle

  const f32x4 zero = {0.f, 0.f, 0.f, 0.f};
  const s16x4 ones = {(short)0x3F80, (short)0x3F80, (short)0x3F80, (short)0x3F80};

  // staging (512 threads): K 2 issues (64 rows x 128B each), V 2 issues
  // (32 rows x 256B each); swizzle terms hoisted (gk&7==k_r, gv&15 const/i).
  const int k_r = lane >> 3, k_c = lane & 7;    // K: 8-row slab, 8 16B granules
  const int v_r = lane >> 4, v_c = lane & 15;   // V: 4-row slab, 16 16B granules
  const int ksw = (k_c ^ k_r) * 8;
  const int vsw = (v_c ^ ((wave * 4 + v_r) & 15)) * 8;
  auto stage = [&](int kb, int bi) {
#pragma unroll
    for (int i = 0; i < 2; i++) {
      const int gk = i * 64 + wave * 8 + k_r;
      cp16(K + (size_t)(kb + gk) * HD + ksw, &Ks[bi][(i * 64 + wave * 8) * 64]);
      const int gv = i * 32 + wave * 4 + v_r;
      cp16(Vt + (size_t)gv * LL + kb + vsw, &Vs[bi][(i * 32 + wave * 4) * 128]);
    }
  };

  // pack 4 f32 -> 4 truncated bf16 via 2 x v_perm_b32
  auto pack4 = [&](const float* p) {
    union { float f; unsigned u; } a0, a1, a2, a3;
    a0.f = p[0]; a1.f = p[1]; a2.f = p[2]; a3.f = p[3];
    union { s16x4 v; unsigned u[2]; } r;
    r.u[0] = __builtin_amdgcn_perm(a1.u, a0.u, 0x07060302u);
    r.u[1] = __builtin_amdgcn_perm(a3.u, a2.u, 0x07060302u);
    return r.v;
  };

  for (int phase = 0; phase < 2; phase++) {
    const int qg = phase == 0 ? (15 - pi) : pi;  // heavy first
    const int qw = qg * 128 + wave * 16;         // this wave's 16 queries
    const int tiles = qg + 1;                    // 128-key tiles

    s16x8 qf[2];
#pragma unroll
    for (int s = 0; s < 2; s++)
      qf[s] = *(const s16x8*)(Q + (size_t)(qw + c16) * HD + s * 32 + quad * 8);

    f32x4 o[4];
#pragma unroll
    for (int j4 = 0; j4 < 4; j4++) o[j4] = zero;
    f32x4 ol = zero;

    stage(0, 0);
    __syncthreads();  // drain tile 0 (also isolates phase 0's last readers)

    for (int t = 0; t < tiles; t++) {
      const int kb = t * 128;
      if (t + 1 < tiles) stage(kb + 128, (t + 1) & 1);
      const short* Kt = &Ks[t & 1][0];
      const short* Vv = &Vs[t & 1][0];

      // causal bounds (wave-uniform): this wave covers queries qw..qw+15
      const int D = qw - kb;                       // >= 0 within tiles range
      const int jm = min((D >> 4) + 1, 8);
      const int jb = D >> 4;

#pragma unroll
      for (int j = 0; j < 8; j++) {
        if (j >= jm) continue;  // wave-uniform skip
        s16x8 kf0 = *(const s16x8*)&Kt[(j * 16 + c16) * 64 + ((quad ^ sw) * 8)];
        s16x8 kf1 = *(const s16x8*)&Kt[(j * 16 + c16) * 64 + (((4 + quad) ^ sw) * 8)];
        s16x4 va[4];
#pragma unroll
        for (int j4 = 0; j4 < 4; j4++)
          va[j4] = *(const s16x4*)&Vv[(j4 * 16 + c16) * 128 +
                                      (((2 * j + (quad >> 1)) ^ c16) * 8) + (quad & 1) * 4];
        f32x4 s = __builtin_amdgcn_mfma_f32_16x16x32_bf16(kf0, qf[0], zero, 0, 0, 0);
        s = __builtin_amdgcn_mfma_f32_16x16x32_bf16(kf1, qf[1], s, 0, 0, 0);
        float p[4];
#pragma unroll
        for (int r = 0; r < 4; r++) p[r] = __builtin_amdgcn_exp2f(s[r]);
        if (j == jb) {
          const int thr = c16 + D - j * 16 - quad * 4;
#pragma unroll
          for (int r = 0; r < 4; r++)
            if (r > thr) p[r] = 0.f;
        }
        s16x4 pb = pack4(p);
        ol = __builtin_amdgcn_mfma_f32_16x16x16bf16_1k(ones, pb, ol, 0, 0, 0);
#pragma unroll
        for (int j4 = 0; j4 < 4; j4++)
          o[j4] = __builtin_amdgcn_mfma_f32_16x16x16bf16_1k(va[j4], pb, o[j4], 0, 0, 0);
      }

      __syncthreads();  // readers done with buf t; drains t+1 staging
    }

    const int b = bh >> 4, h2 = bh & 15;
    const float inv = 1.0f / ol[0];
    const int q = qw + c16;
#pragma unroll
    for (int j4 = 0; j4 < 4; j4++) {
      s16x4 ov;
#pragma unroll
      for (int r = 0; r < 4; r++) ov[r] = f2bf(o[j4][r] * inv);
      *(s16x4*)&Cb[(size_t)(b * LL + q) * DD + h2 * HD + j4 * 16 + quad * 4] = ov;
    }
  }
}

// ---------------- launch ----------------
extern "C" void kernel_launch(void* const* d_in, const int* in_sizes, int n_in,
                              void* d_out, int out_size, void* d_ws, size_t ws_size,
                              hipStream_t stream) {
  const float* x = (const float*)d_in[0];
  const float* wqkv = (const float*)d_in[1];
  const float* wout = (const float*)d_in[2];
  float* out = (float*)d_out;

  const size_t NX = (size_t)BB * LL * DD;  // 8388608
  short* xb = (short*)d_ws;
  short* wqkvb = xb + NX;
  short* woutb = wqkvb + (size_t)3 * DD * DD;
  short* qb = woutb + (size_t)DD * DD;
  short* kb = qb + NX;
  short* vb = kb + NX;   // V transposed: [B,H,HD,L]
  short* cb = vb + NX;
  // total: 92,274,688 bytes of d_ws

  f2b_kernel<<<dim3((unsigned)(NX / 4 / 256)), 256, 0, stream>>>(x, xb, (int)(NX / 4));
  f2b_kernel<<<dim3(3 * DD * DD / 4 / 256), 256, 0, stream>>>(wqkv, wqkvb, 3 * DD * DD / 4);
  f2b_kernel<<<dim3(DD * DD / 4 / 256), 256, 0, stream>>>(wout, woutb, DD * DD / 4);

  // gemm0: 256x256 tiles, 8-phase deep pipeline -> 12 x 32 = 384 blocks
  gemm8<256, 0><<<dim3(3 * DD / 256, BB * LL / 256), 512, 0, stream>>>(
      xb, wqkvb, DD, 3 * DD, qb, kb, vb, nullptr);
  attn_kernel<<<dim3(8, BB * HH), 512, 0, stream>>>(qb, kb, vb, cb);
  // gemm1: 128x256 tiles, 8-phase -> 4 x 64 = 256 blocks = one exact round
  gemm8<128, 1><<<dim3(DD / 256, BB * LL / 128), 512, 0, stream>>>(
      cb, woutb, DD, DD, nullptr, nullptr, nullptr, out);
}

// Round 6
// 239.931 us; speedup vs baseline: 1.1104x; 1.0849x over previous
//
#include <hip/hip_runtime.h>

#define BB 4
#define LL 2048
#define DD 1024
#define HH 16
#define HD 64

typedef __attribute__((ext_vector_type(8))) short s16x8;
typedef __attribute__((ext_vector_type(4))) short s16x4;
typedef __attribute__((ext_vector_type(4))) float f32x4;

#define SCALE_LOG2E 0.18033688011112042f  // 0.125 * log2(e), folded into Q

__device__ __forceinline__ short f2bf(float f) {
  union { float f; unsigned u; } c;
  c.f = f;
  return (short)((c.u + 0x7fffu + ((c.u >> 16) & 1u)) >> 16);  // RNE
}

// async global -> LDS, 16B per lane. LDS dest = wave-uniform base + lane*16.
__device__ __forceinline__ void cp16(const void* g, void* l) {
  __builtin_amdgcn_global_load_lds(
      (const __attribute__((address_space(1))) void*)g,
      (__attribute__((address_space(3))) void*)l, 16, 0, 0);
}

// ---------------- fp32 -> bf16 convert, all three tensors, one launch ------
// segments (in 256-thread float4 blocks): x 8192 | wqkv 3072 | wout 1024.
__global__ __launch_bounds__(256) void f2b_all(const float* __restrict__ x,
                                               const float* __restrict__ wqkv,
                                               const float* __restrict__ wout,
                                               short* __restrict__ xb,
                                               short* __restrict__ wqkvb,
                                               short* __restrict__ woutb) {
  const int bid = blockIdx.x;
  const float* in;
  short* out;
  int i0;
  if (bid < 8192) {
    in = x; out = xb; i0 = bid;
  } else if (bid < 8192 + 3072) {
    in = wqkv; out = wqkvb; i0 = bid - 8192;
  } else {
    in = wout; out = woutb; i0 = bid - (8192 + 3072);
  }
  const int i = i0 * 256 + threadIdx.x;
  float4 v = ((const float4*)in)[i];
  s16x4 o;
  o[0] = f2bf(v.x);
  o[1] = f2bf(v.y);
  o[2] = f2bf(v.z);
  o[3] = f2bf(v.w);
  ((s16x4*)out)[i] = o;
}

// ---------------- GEMM: C[M,N] = A[M,K] * B[N,K]^T (bf16 in, MFMA) ----------
// r2 structure (proven 74.6 us gemm0) with 3-deep LDS rotation: 48 KB LDS ->
// 3 blocks/CU (was 2 at 64 KB). Blocks are NOT barrier-synced with each
// other, so one block's MFMA phase overlaps another's LDS burst — attacks
// the LDS-pipe serialization (per K-step per CU: 64 KB reads + 32 KB stage
// writes ~= the whole step time at 85 B/cy).
// Ledger: stage distance 2; steady vmcnt(4) at phase end retires exactly
// t+1's 4 loads (t+2's stay in flight); tail vmcnt(0) at T-2. Rewrite of
// buf[(t+2)%3] is issued after the barrier following its last read -> safe.
// SWIZZLE (measured 0 conflicts r2-r5): granule ^= (row>>1)&3 both sides.
// MODE 0: scatter bf16 into Q (pre-scaled) / K [B,H,L,HD], V^T [B,H,HD,L].
// MODE 1: fp32 row-major out.
template <int MODE>
__global__ __launch_bounds__(256, 3) void gemm_bt(const short* __restrict__ A,
                                                  const short* __restrict__ Bm,
                                                  int K, int N,
                                                  short* __restrict__ qo,
                                                  short* __restrict__ ko,
                                                  short* __restrict__ vo,
                                                  float* __restrict__ fo) {
  __shared__ __align__(16) short As[3][128 * 32];
  __shared__ __align__(16) short Bs[3][128 * 32];
  const int tid = threadIdx.x;
  const int m0 = blockIdx.y * 128, n0 = blockIdx.x * 128;
  const int wave = tid >> 6, lane = tid & 63;
  const int quad = lane >> 4, c16 = lane & 15;
  const int wr = (wave >> 1) * 64, wc = (wave & 1) * 64;

  f32x4 zero = {0.f, 0.f, 0.f, 0.f};
  f32x4 acc[4][4];
#pragma unroll
  for (int i = 0; i < 4; i++)
#pragma unroll
    for (int j = 0; j < 4; j++) acc[i][j] = zero;

  const int row1 = tid >> 2;                            // 64 rows x 4 16B-granules
  const int gsw = ((tid & 3) ^ ((tid >> 3) & 3)) * 8;   // xor-swizzled src granule
  const short* Ag = A + (size_t)(m0 + row1) * K + gsw;
  const short* Bg = Bm + (size_t)(n0 + row1) * K + gsw;
  const int rsw = (quad ^ ((c16 >> 1) & 3)) * 8;        // xor-swizzled read offset

  auto stage = [&](int t, int bi) {
    const int k0 = t << 5;
    cp16(Ag + k0, As[bi] + wave * 512);
    cp16(Ag + (size_t)64 * K + k0, As[bi] + 2048 + wave * 512);
    cp16(Bg + k0, Bs[bi] + wave * 512);
    cp16(Bg + (size_t)64 * K + k0, Bs[bi] + 2048 + wave * 512);
  };

  const int T = K >> 5;  // 32 K-tiles at K=1024
  stage(0, 0);
  stage(1, 1);
  asm volatile("s_waitcnt vmcnt(4)" ::: "memory");  // K-tile 0 resident
  __builtin_amdgcn_s_barrier();
  asm volatile("" ::: "memory");

  int bcur = 0;
  for (int t = 0; t < T; t++) {
    const short* Asb = As[bcur];
    const short* Bsb = Bs[bcur];
    s16x8 af[4], bfv[4];
#pragma unroll
    for (int i = 0; i < 4; i++)
      af[i] = *(const s16x8*)&Asb[(wr + i * 16 + c16) * 32 + rsw];
#pragma unroll
    for (int j = 0; j < 4; j++)
      bfv[j] = *(const s16x8*)&Bsb[(wc + j * 16 + c16) * 32 + rsw];
    if (t + 2 < T) {
      int b2 = bcur + 2;
      if (b2 >= 3) b2 -= 3;
      stage(t + 2, b2);
    }
    __builtin_amdgcn_s_setprio(1);
#pragma unroll
    for (int i = 0; i < 4; i++)
#pragma unroll
      for (int j = 0; j < 4; j++)
        acc[i][j] = __builtin_amdgcn_mfma_f32_16x16x32_bf16(af[i], bfv[j], acc[i][j], 0, 0, 0);
    __builtin_amdgcn_s_setprio(0);
    // retire exactly next K-tile's staging; keep newest 4 in flight
    if (t < T - 2) asm volatile("s_waitcnt vmcnt(4)" ::: "memory");
    else if (t == T - 2) asm volatile("s_waitcnt vmcnt(0)" ::: "memory");
    __builtin_amdgcn_s_barrier();
    asm volatile("" ::: "memory");
    bcur = (bcur == 2) ? 0 : bcur + 1;
  }

  if (MODE == 0) {
#pragma unroll
    for (int j = 0; j < 4; j++) {
      const int gn = n0 + wc + j * 16 + c16;       // 0..3071
      const int which = gn >> 10;
      const int h = (gn >> 6) & 15;
      const int hd = gn & 63;
      if (which == 2) {
#pragma unroll
        for (int i = 0; i < 4; i++) {
          const int gm = m0 + wr + i * 16 + quad * 4;  // 4 consecutive rows
          const int b = gm >> 11, l = gm & 2047;       // l..l+3 contiguous, 8B-aligned
          s16x4 vv;
#pragma unroll
          for (int r = 0; r < 4; r++) vv[r] = f2bf(acc[i][j][r]);
          *(s16x4*)&vo[((size_t)((b << 4) + h) * HD + hd) * LL + l] = vv;
        }
      } else {
        short* dst = which == 0 ? qo : ko;
        const float sc = which == 0 ? SCALE_LOG2E : 1.0f;  // fold softmax scale into Q
#pragma unroll
        for (int i = 0; i < 4; i++)
#pragma unroll
          for (int r = 0; r < 4; r++) {
            const int gm = m0 + wr + i * 16 + quad * 4 + r;
            const int b = gm >> 11, l = gm & 2047;
            dst[((size_t)((b << 4) + h) * LL + l) * HD + hd] = f2bf(acc[i][j][r] * sc);
          }
      }
    }
  } else {
#pragma unroll
    for (int i = 0; i < 4; i++)
#pragma unroll
      for (int r = 0; r < 4; r++) {
        const int gm = m0 + wr + i * 16 + quad * 4 + r;
#pragma unroll
        for (int j = 0; j < 4; j++) {
          const int gn = n0 + wc + j * 16 + c16;
          fo[(size_t)gm * N + gn] = acc[i][j][r];
        }
      }
  }
}

// ---------------- flash attention: paired q-blocks, 128-key tiles ----------
// Causal load balance: block pi processes q-block (15-pi) then q-block pi —
// exactly 17 tile-rounds per block, grid 8x64 = 512 blocks = 2/CU.
// 8 waves x 16 queries each -> 16 waves/CU = 4/SIMD for latency hiding.
// S^T = K*Q^T per 16-key block; P in registers; Q pre-scaled; p = 2^s
// (exact after p/l norm); denom via ones-A MFMA on the matrix pipe.
__global__ __launch_bounds__(512, 4) void attn_kernel(const short* __restrict__ Qb,
                                                      const short* __restrict__ Kb,
                                                      const short* __restrict__ Vtb,
                                                      short* __restrict__ Cb) {
  const int pi = blockIdx.x;  // 0..7
  const int bh = blockIdx.y;  // 0..63
  const int tid = threadIdx.x;
  const int wave = tid >> 6, lane = tid & 63;  // wave 0..7
  const int quad = lane >> 4, c16 = lane & 15;
  const int sw = c16 & 7;  // K-read swizzle term
  const size_t base = (size_t)bh * LL * HD;
  const short* Q = Qb + base;
  const short* K = Kb + base;
  const short* Vt = Vtb + base;  // [HD][LL]

  __shared__ __align__(16) short Ks[2][128 * 64];  // [key][hd], 3-bit swizzle
  __shared__ __align__(16) short Vs[2][64 * 128];  // [hd][key], 4-bit swizzle

  const f32x4 zero = {0.f, 0.f, 0.f, 0.f};
  const s16x4 ones = {(short)0x3F80, (short)0x3F80, (short)0x3F80, (short)0x3F80};

  // staging (512 threads): K 2 issues (64 rows x 128B each), V 2 issues
  // (32 rows x 256B each); swizzle terms hoisted (gk&7==k_r, gv&15 const/i).
  const int k_r = lane >> 3, k_c = lane & 7;    // K: 8-row slab, 8 16B granules
  const int v_r = lane >> 4, v_c = lane & 15;   // V: 4-row slab, 16 16B granules
  const int ksw = (k_c ^ k_r) * 8;
  const int vsw = (v_c ^ ((wave * 4 + v_r) & 15)) * 8;
  auto stage = [&](int kb, int bi) {
#pragma unroll
    for (int i = 0; i < 2; i++) {
      const int gk = i * 64 + wave * 8 + k_r;
      cp16(K + (size_t)(kb + gk) * HD + ksw, &Ks[bi][(i * 64 + wave * 8) * 64]);
      const int gv = i * 32 + wave * 4 + v_r;
      cp16(Vt + (size_t)gv * LL + kb + vsw, &Vs[bi][(i * 32 + wave * 4) * 128]);
    }
  };

  // pack 4 f32 -> 4 truncated bf16 via 2 x v_perm_b32
  auto pack4 = [&](const float* p) {
    union { float f; unsigned u; } a0, a1, a2, a3;
    a0.f = p[0]; a1.f = p[1]; a2.f = p[2]; a3.f = p[3];
    union { s16x4 v; unsigned u[2]; } r;
    r.u[0] = __builtin_amdgcn_perm(a1.u, a0.u, 0x07060302u);
    r.u[1] = __builtin_amdgcn_perm(a3.u, a2.u, 0x07060302u);
    return r.v;
  };

  for (int phase = 0; phase < 2; phase++) {
    const int qg = phase == 0 ? (15 - pi) : pi;  // heavy first
    const int qw = qg * 128 + wave * 16;         // this wave's 16 queries
    const int tiles = qg + 1;                    // 128-key tiles

    s16x8 qf[2];
#pragma unroll
    for (int s = 0; s < 2; s++)
      qf[s] = *(const s16x8*)(Q + (size_t)(qw + c16) * HD + s * 32 + quad * 8);

    f32x4 o[4];
#pragma unroll
    for (int j4 = 0; j4 < 4; j4++) o[j4] = zero;
    f32x4 ol = zero;

    stage(0, 0);
    __syncthreads();  // drain tile 0 (also isolates phase 0's last readers)

    for (int t = 0; t < tiles; t++) {
      const int kb = t * 128;
      if (t + 1 < tiles) stage(kb + 128, (t + 1) & 1);
      const short* Kt = &Ks[t & 1][0];
      const short* Vv = &Vs[t & 1][0];

      // causal bounds (wave-uniform): this wave covers queries qw..qw+15
      const int D = qw - kb;                       // >= 0 within tiles range
      const int jm = min((D >> 4) + 1, 8);
      const int jb = D >> 4;

#pragma unroll
      for (int j = 0; j < 8; j++) {
        if (j >= jm) continue;  // wave-uniform skip
        s16x8 kf0 = *(const s16x8*)&Kt[(j * 16 + c16) * 64 + ((quad ^ sw) * 8)];
        s16x8 kf1 = *(const s16x8*)&Kt[(j * 16 + c16) * 64 + (((4 + quad) ^ sw) * 8)];
        s16x4 va[4];
#pragma unroll
        for (int j4 = 0; j4 < 4; j4++)
          va[j4] = *(const s16x4*)&Vv[(j4 * 16 + c16) * 128 +
                                      (((2 * j + (quad >> 1)) ^ c16) * 8) + (quad & 1) * 4];
        f32x4 s = __builtin_amdgcn_mfma_f32_16x16x32_bf16(kf0, qf[0], zero, 0, 0, 0);
        s = __builtin_amdgcn_mfma_f32_16x16x32_bf16(kf1, qf[1], s, 0, 0, 0);
        float p[4];
#pragma unroll
        for (int r = 0; r < 4; r++) p[r] = __builtin_amdgcn_exp2f(s[r]);
        if (j == jb) {
          const int thr = c16 + D - j * 16 - quad * 4;
#pragma unroll
          for (int r = 0; r < 4; r++)
            if (r > thr) p[r] = 0.f;
        }
        s16x4 pb = pack4(p);
        ol = __builtin_amdgcn_mfma_f32_16x16x16bf16_1k(ones, pb, ol, 0, 0, 0);
#pragma unroll
        for (int j4 = 0; j4 < 4; j4++)
          o[j4] = __builtin_amdgcn_mfma_f32_16x16x16bf16_1k(va[j4], pb, o[j4], 0, 0, 0);
      }

      __syncthreads();  // readers done with buf t; drains t+1 staging
    }

    const int b = bh >> 4, h2 = bh & 15;
    const float inv = 1.0f / ol[0];
    const int q = qw + c16;
#pragma unroll
    for (int j4 = 0; j4 < 4; j4++) {
      s16x4 ov;
#pragma unroll
      for (int r = 0; r < 4; r++) ov[r] = f2bf(o[j4][r] * inv);
      *(s16x4*)&Cb[(size_t)(b * LL + q) * DD + h2 * HD + j4 * 16 + quad * 4] = ov;
    }
  }
}

// ---------------- launch ----------------
extern "C" void kernel_launch(void* const* d_in, const int* in_sizes, int n_in,
                              void* d_out, int out_size, void* d_ws, size_t ws_size,
                              hipStream_t stream) {
  const float* x = (const float*)d_in[0];
  const float* wqkv = (const float*)d_in[1];
  const float* wout = (const float*)d_in[2];
  float* out = (float*)d_out;

  const size_t NX = (size_t)BB * LL * DD;  // 8388608
  short* xb = (short*)d_ws;
  short* wqkvb = xb + NX;
  short* woutb = wqkvb + (size_t)3 * DD * DD;
  short* qb = woutb + (size_t)DD * DD;
  short* kb = qb + NX;
  short* vb = kb + NX;   // V transposed: [B,H,HD,L]
  short* cb = vb + NX;
  // total: 92,274,688 bytes of d_ws

  // all three fp32->bf16 conversions in ONE launch (saves 2 launch gaps)
  f2b_all<<<dim3(8192 + 3072 + 1024), 256, 0, stream>>>(x, wqkv, wout, xb, wqkvb, woutb);

  gemm_bt<0><<<dim3(3 * DD / 128, BB * LL / 128), 256, 0, stream>>>(
      xb, wqkvb, DD, 3 * DD, qb, kb, vb, nullptr);
  attn_kernel<<<dim3(8, BB * HH), 512, 0, stream>>>(qb, kb, vb, cb);
  gemm_bt<1><<<dim3(DD / 128, BB * LL / 128), 256, 0, stream>>>(
      cb, woutb, DD, DD, nullptr, nullptr, nullptr, out);
}